// Round 1
// baseline (901.216 us; speedup 1.0000x reference)
//
#include <hip/hip_runtime.h>
#include <hip/hip_bf16.h>
#include <math.h>

#define NHID 128
#define NCLASS 40

// ----------------------------- CSR build --------------------------------

__global__ __launch_bounds__(256) void hist_kernel(const int* __restrict__ dst,
                                                   int* __restrict__ cnt, int E) {
    int e = blockIdx.x * 256 + threadIdx.x;
    if (e < E) atomicAdd(&cnt[dst[e]], 1);
}

// Per-node: dinv = rsqrt(cnt+1); allocate contiguous CSR region via block scan
// + one atomic per block (avoids 100k serialized atomics on one counter).
__global__ __launch_bounds__(256) void build_nodes_kernel(
        const int* __restrict__ cnt, int* __restrict__ start,
        int* __restrict__ cursor, float* __restrict__ dinv,
        int* __restrict__ total, int N) {
    int i = blockIdx.x * 256 + threadIdx.x;
    int v = (i < N) ? cnt[i] : 0;
    __shared__ int sc[256];
    sc[threadIdx.x] = v;
    __syncthreads();
    for (int off = 1; off < 256; off <<= 1) {
        int t = (threadIdx.x >= off) ? sc[threadIdx.x - off] : 0;
        __syncthreads();
        sc[threadIdx.x] += t;
        __syncthreads();
    }
    int incl = sc[threadIdx.x];
    __shared__ int base;
    if (threadIdx.x == 255) base = atomicAdd(total, incl);
    __syncthreads();
    if (i < N) {
        int s = base + incl - v;
        start[i] = s;
        cursor[i] = s;
        dinv[i] = rsqrtf((float)(cnt[i] + 1));  // +1 self-loop; deg >= 1 always
    }
}

__global__ __launch_bounds__(256) void fill_kernel(const int* __restrict__ src,
                                                   const int* __restrict__ dst,
                                                   int* __restrict__ cursor,
                                                   int* __restrict__ col, int E) {
    int e = blockIdx.x * 256 + threadIdx.x;
    if (e < E) {
        int p = atomicAdd(&cursor[dst[e]], 1);
        col[p] = src[e];
    }
}

// ------------------------------- GEMM -----------------------------------
// C[M x N] = A[M x K] * W[K x N], fp32 (no fp32 MFMA on CDNA4 -> vector ALU).
// Block tile: BM = RG*4 rows x NT cols, 256 threads, per-thread 4 rows x 8 cols.
// KC=32 K-chunks of A and W staged in LDS.
template <int K, int NT, int CG, int RG, bool GUARDN>
__global__ __launch_bounds__(256) void gemm_kernel(const float* __restrict__ A,
                                                   const float* __restrict__ W,
                                                   float* __restrict__ C,
                                                   int M, int N) {
    constexpr int KC = 32;
    constexpr int BM = RG * 4;
    __shared__ float As[BM][KC + 4];  // +4 pad: conflict-free, keeps 16B align
    __shared__ float Ws[KC][NT];
    const int t = threadIdx.x;
    const int cg = t & (CG - 1);
    const int rg = t / CG;
    const int row0 = blockIdx.x * BM;

    float acc[4][8];
#pragma unroll
    for (int r = 0; r < 4; ++r)
#pragma unroll
        for (int j = 0; j < 8; ++j) acc[r][j] = 0.f;

    for (int k0 = 0; k0 < K; k0 += KC) {
        // stage A chunk (BM x KC), float4 loads, coalesced
#pragma unroll
        for (int i = 0; i < BM / 32; ++i) {
            int fi = t + i * 256;
            int row = fi >> 3;  // KC/4 = 8 float4 per row
            int kq = fi & 7;
            int grow = row0 + row;
            if (grow >= M) grow = M - 1;
            float4 v = *reinterpret_cast<const float4*>(&A[(size_t)grow * K + k0 + kq * 4]);
            *reinterpret_cast<float4*>(&As[row][kq * 4]) = v;
        }
        // stage W chunk (KC x NT)
        if (!GUARDN) {
#pragma unroll
            for (int i = 0; i < (KC * NT / 4) / 256; ++i) {
                int fi = t + i * 256;
                int kr = fi / (NT / 4);
                int cq = fi % (NT / 4);
                *reinterpret_cast<float4*>(&Ws[kr][cq * 4]) =
                    *reinterpret_cast<const float4*>(&W[(size_t)(k0 + kr) * N + cq * 4]);
            }
        } else {
            for (int fi = t; fi < KC * NT; fi += 256) {
                int kr = fi / NT;
                int c = fi - kr * NT;
                Ws[kr][c] = (c < N) ? W[(size_t)(k0 + kr) * N + c] : 0.f;
            }
        }
        __syncthreads();

#pragma unroll 8
        for (int kk = 0; kk < KC; ++kk) {
            float4 w0 = *reinterpret_cast<const float4*>(&Ws[kk][cg * 8]);
            float4 w1 = *reinterpret_cast<const float4*>(&Ws[kk][cg * 8 + 4]);
#pragma unroll
            for (int r = 0; r < 4; ++r) {
                float a = As[rg * 4 + r][kk];
                acc[r][0] = fmaf(a, w0.x, acc[r][0]);
                acc[r][1] = fmaf(a, w0.y, acc[r][1]);
                acc[r][2] = fmaf(a, w0.z, acc[r][2]);
                acc[r][3] = fmaf(a, w0.w, acc[r][3]);
                acc[r][4] = fmaf(a, w1.x, acc[r][4]);
                acc[r][5] = fmaf(a, w1.y, acc[r][5]);
                acc[r][6] = fmaf(a, w1.z, acc[r][6]);
                acc[r][7] = fmaf(a, w1.w, acc[r][7]);
            }
        }
        __syncthreads();
    }

    // store
#pragma unroll
    for (int r = 0; r < 4; ++r) {
        int grow = row0 + rg * 4 + r;
        if (grow < M) {
            if (!GUARDN) {
                float4 v0 = make_float4(acc[r][0], acc[r][1], acc[r][2], acc[r][3]);
                float4 v1 = make_float4(acc[r][4], acc[r][5], acc[r][6], acc[r][7]);
                *reinterpret_cast<float4*>(&C[(size_t)grow * N + cg * 8]) = v0;
                *reinterpret_cast<float4*>(&C[(size_t)grow * N + cg * 8 + 4]) = v1;
            } else {
#pragma unroll
                for (int j = 0; j < 8; ++j) {
                    int c = cg * 8 + j;
                    if (c < N) C[(size_t)grow * N + c] = acc[r][j];
                }
            }
        }
    }
}

// --------------------------- Aggregation --------------------------------
// One wave per node. F=128: float2 per lane (64*8B = 512B contiguous gather
// per neighbor). agg[i] = dinv[i]*(sum_j dinv[j]*m[j] + dinv[i]*m[i]); then
// bias + ReLU fused.
__global__ __launch_bounds__(256) void agg_h_kernel(
        const float* __restrict__ m, const int* __restrict__ col,
        const int* __restrict__ start, const int* __restrict__ cnt,
        const float* __restrict__ dinv, const float* __restrict__ bias,
        float* __restrict__ out, int N) {
    int w = (int)((blockIdx.x * 256 + threadIdx.x) >> 6);
    int lane = threadIdx.x & 63;
    if (w >= N) return;
    int s = start[w];
    int e = s + cnt[w];
    float ax = 0.f, ay = 0.f;
    for (int p = s; p < e; ++p) {
        int j = col[p];             // wave-uniform
        float wt = dinv[j];         // wave-uniform
        float2 v = *reinterpret_cast<const float2*>(&m[(size_t)j * NHID + lane * 2]);
        ax = fmaf(wt, v.x, ax);
        ay = fmaf(wt, v.y, ay);
    }
    float di = dinv[w];
    float2 mi = *reinterpret_cast<const float2*>(&m[(size_t)w * NHID + lane * 2]);
    ax = fmaf(di, mi.x, ax);
    ay = fmaf(di, mi.y, ay);
    float2 o;
    o.x = fmaxf(fmaf(di, ax, bias[lane * 2]), 0.f);
    o.y = fmaxf(fmaf(di, ay, bias[lane * 2 + 1]), 0.f);
    *reinterpret_cast<float2*>(&out[(size_t)w * NHID + lane * 2]) = o;
}

// Final layer: F=40 + bias + ReLU + log_softmax (wave shuffle reduce).
__global__ __launch_bounds__(256) void agg_out_kernel(
        const float* __restrict__ m, const int* __restrict__ col,
        const int* __restrict__ start, const int* __restrict__ cnt,
        const float* __restrict__ dinv, const float* __restrict__ bias,
        float* __restrict__ out, int N) {
    int w = (int)((blockIdx.x * 256 + threadIdx.x) >> 6);
    int lane = threadIdx.x & 63;
    if (w >= N) return;
    bool act = lane < NCLASS;
    int cl = act ? lane : 0;
    int s = start[w];
    int e = s + cnt[w];
    float a = 0.f;
    for (int p = s; p < e; ++p) {
        int j = col[p];
        float wt = dinv[j];
        a = fmaf(wt, m[(size_t)j * NCLASS + cl], a);
    }
    float di = dinv[w];
    a = fmaf(di, m[(size_t)w * NCLASS + cl], a);
    float h = fmaxf(fmaf(di, a, bias[cl]), 0.f);
    float hm = act ? h : -INFINITY;
#pragma unroll
    for (int off = 32; off; off >>= 1) hm = fmaxf(hm, __shfl_xor(hm, off, 64));
    float ex = act ? expf(h - hm) : 0.f;
    float se = ex;
#pragma unroll
    for (int off = 32; off; off >>= 1) se += __shfl_xor(se, off, 64);
    if (act) out[(size_t)w * NCLASS + lane] = h - hm - logf(se);
}

// ------------------------------ launch -----------------------------------

extern "C" void kernel_launch(void* const* d_in, const int* in_sizes, int n_in,
                              void* d_out, int out_size, void* d_ws, size_t ws_size,
                              hipStream_t stream) {
    const float* x  = (const float*)d_in[0];
    const int*   ei = (const int*)d_in[1];
    const float* W0 = (const float*)d_in[2];
    const float* b0 = (const float*)d_in[3];
    const float* W1 = (const float*)d_in[4];
    const float* b1 = (const float*)d_in[5];
    const float* W2 = (const float*)d_in[6];
    const float* b2 = (const float*)d_in[7];
    float* out = (float*)d_out;

    const int NFEATr = 256;
    const int N = in_sizes[0] / NFEATr;  // 100000
    const int E = in_sizes[1] / 2;       // 1600000
    const int* src = ei;
    const int* dst = ei + E;

    // workspace carve (need ~111 MB)
    char* p = (char*)d_ws;
    auto alloc = [&](size_t bytes) -> void* {
        void* r = (void*)p;
        p += (bytes + 255) & ~(size_t)255;
        return r;
    };
    int*   cnt    = (int*)alloc((size_t)N * 4);
    int*   start  = (int*)alloc((size_t)N * 4);
    int*   cursor = (int*)alloc((size_t)N * 4);
    float* dinv   = (float*)alloc((size_t)N * 4);
    int*   total  = (int*)alloc(256);
    int*   col    = (int*)alloc((size_t)E * 4);
    float* mbuf   = (float*)alloc((size_t)N * NHID * 4);
    float* hbuf   = (float*)alloc((size_t)N * NHID * 4);

    hipMemsetAsync(cnt, 0, (size_t)N * 4, stream);
    hipMemsetAsync(total, 0, 4, stream);

    int ebl = (E + 255) / 256;
    int nbl = (N + 255) / 256;
    hist_kernel<<<ebl, 256, 0, stream>>>(dst, cnt, E);
    build_nodes_kernel<<<nbl, 256, 0, stream>>>(cnt, start, cursor, dinv, total, N);
    fill_kernel<<<ebl, 256, 0, stream>>>(src, dst, cursor, col, E);

    int gbl64 = (N + 63) / 64;
    int gbl128 = (N + 127) / 128;
    int abl = (N + 3) / 4;  // 4 waves/block, 1 node/wave

    // layer 0: x[N,256] @ W0[256,128] -> mbuf; agg+bias+relu -> hbuf
    gemm_kernel<256, 128, 16, 16, false><<<gbl64, 256, 0, stream>>>(x, W0, mbuf, N, NHID);
    agg_h_kernel<<<abl, 256, 0, stream>>>(mbuf, col, start, cnt, dinv, b0, hbuf, N);

    // layer 1: hbuf @ W1[128,128] -> mbuf; agg+bias+relu -> hbuf
    gemm_kernel<128, 128, 16, 16, false><<<gbl64, 256, 0, stream>>>(hbuf, W1, mbuf, N, NHID);
    agg_h_kernel<<<abl, 256, 0, stream>>>(mbuf, col, start, cnt, dinv, b1, hbuf, N);

    // layer 2: hbuf @ W2[128,40] -> mbuf(40-wide); agg+bias+relu+log_softmax -> out
    gemm_kernel<128, 64, 8, 32, true><<<gbl128, 256, 0, stream>>>(hbuf, W2, mbuf, N, NCLASS);
    agg_out_kernel<<<abl, 256, 0, stream>>>(mbuf, col, start, cnt, dinv, b2, out, N);
}

// Round 2
// 614.219 us; speedup vs baseline: 1.4673x; 1.4673x over previous
//
#include <hip/hip_runtime.h>
#include <hip/hip_bf16.h>
#include <hip/hip_fp16.h>
#include <math.h>

#define NHID 128
#define NCLASS 40

// ----------------------------- CSR build --------------------------------

__global__ __launch_bounds__(256) void hist_kernel(const int* __restrict__ dst,
                                                   int* __restrict__ cnt, int E) {
    int e = blockIdx.x * 256 + threadIdx.x;
    if (e < E) atomicAdd(&cnt[dst[e]], 1);
}

// Per-node: dinv = rsqrt(cnt+1); allocate contiguous CSR region via block scan
// + one atomic per block.
__global__ __launch_bounds__(256) void build_nodes_kernel(
        const int* __restrict__ cnt, int* __restrict__ start,
        int* __restrict__ cursor, float* __restrict__ dinv,
        int* __restrict__ total, int N) {
    int i = blockIdx.x * 256 + threadIdx.x;
    int v = (i < N) ? cnt[i] : 0;
    __shared__ int sc[256];
    sc[threadIdx.x] = v;
    __syncthreads();
    for (int off = 1; off < 256; off <<= 1) {
        int t = (threadIdx.x >= off) ? sc[threadIdx.x - off] : 0;
        __syncthreads();
        sc[threadIdx.x] += t;
        __syncthreads();
    }
    int incl = sc[threadIdx.x];
    __shared__ int base;
    if (threadIdx.x == 255) base = atomicAdd(total, incl);
    __syncthreads();
    if (i < N) {
        int s = base + incl - v;
        start[i] = s;
        cursor[i] = s;
        dinv[i] = rsqrtf((float)(cnt[i] + 1));  // +1 self-loop
    }
}

__global__ __launch_bounds__(256) void fill_kernel(const int* __restrict__ src,
                                                   const int* __restrict__ dst,
                                                   int* __restrict__ cursor,
                                                   int* __restrict__ col, int E) {
    int e = blockIdx.x * 256 + threadIdx.x;
    if (e < E) {
        int p = atomicAdd(&cursor[dst[e]], 1);
        col[p] = src[e];
    }
}

// ------------------------------- GEMM -----------------------------------
// C[M x N] = dinv[row] * (A[M x K] * W[K x N]) stored as fp16 ("pre-scaled
// messages"). fp32 accumulate on vector ALU (no fp32 MFMA on CDNA4).
// Block tile: BM = RG*4 rows x NT cols, 256 threads, per-thread 4 rows x 8 cols.
template <int K, int NT, int CG, int RG, bool GUARDN>
__global__ __launch_bounds__(256) void gemm_kernel(const float* __restrict__ A,
                                                   const float* __restrict__ W,
                                                   const float* __restrict__ dinv,
                                                   __half* __restrict__ C,
                                                   int M, int N) {
    constexpr int KC = 32;
    constexpr int BM = RG * 4;
    __shared__ float As[BM][KC + 4];
    __shared__ float Ws[KC][NT];
    const int t = threadIdx.x;
    const int cg = t & (CG - 1);
    const int rg = t / CG;
    const int row0 = blockIdx.x * BM;

    float acc[4][8];
#pragma unroll
    for (int r = 0; r < 4; ++r)
#pragma unroll
        for (int j = 0; j < 8; ++j) acc[r][j] = 0.f;

    for (int k0 = 0; k0 < K; k0 += KC) {
#pragma unroll
        for (int i = 0; i < BM / 32; ++i) {
            int fi = t + i * 256;
            int row = fi >> 3;
            int kq = fi & 7;
            int grow = row0 + row;
            if (grow >= M) grow = M - 1;
            float4 v = *reinterpret_cast<const float4*>(&A[(size_t)grow * K + k0 + kq * 4]);
            *reinterpret_cast<float4*>(&As[row][kq * 4]) = v;
        }
        if (!GUARDN) {
#pragma unroll
            for (int i = 0; i < (KC * NT / 4) / 256; ++i) {
                int fi = t + i * 256;
                int kr = fi / (NT / 4);
                int cq = fi % (NT / 4);
                *reinterpret_cast<float4*>(&Ws[kr][cq * 4]) =
                    *reinterpret_cast<const float4*>(&W[(size_t)(k0 + kr) * N + cq * 4]);
            }
        } else {
            for (int fi = t; fi < KC * NT; fi += 256) {
                int kr = fi / NT;
                int c = fi - kr * NT;
                Ws[kr][c] = (c < N) ? W[(size_t)(k0 + kr) * N + c] : 0.f;
            }
        }
        __syncthreads();

#pragma unroll 8
        for (int kk = 0; kk < KC; ++kk) {
            float4 w0 = *reinterpret_cast<const float4*>(&Ws[kk][cg * 8]);
            float4 w1 = *reinterpret_cast<const float4*>(&Ws[kk][cg * 8 + 4]);
#pragma unroll
            for (int r = 0; r < 4; ++r) {
                float a = As[rg * 4 + r][kk];
                acc[r][0] = fmaf(a, w0.x, acc[r][0]);
                acc[r][1] = fmaf(a, w0.y, acc[r][1]);
                acc[r][2] = fmaf(a, w0.z, acc[r][2]);
                acc[r][3] = fmaf(a, w0.w, acc[r][3]);
                acc[r][4] = fmaf(a, w1.x, acc[r][4]);
                acc[r][5] = fmaf(a, w1.y, acc[r][5]);
                acc[r][6] = fmaf(a, w1.z, acc[r][6]);
                acc[r][7] = fmaf(a, w1.w, acc[r][7]);
            }
        }
        __syncthreads();
    }

#pragma unroll
    for (int r = 0; r < 4; ++r) {
        int grow = row0 + rg * 4 + r;
        if (grow < M) {
            float sc = dinv[grow];
            if (!GUARDN) {
                __half2 h0 = __floats2half2_rn(acc[r][0] * sc, acc[r][1] * sc);
                __half2 h1 = __floats2half2_rn(acc[r][2] * sc, acc[r][3] * sc);
                __half2 h2 = __floats2half2_rn(acc[r][4] * sc, acc[r][5] * sc);
                __half2 h3 = __floats2half2_rn(acc[r][6] * sc, acc[r][7] * sc);
                int4 pk;
                pk.x = *reinterpret_cast<int*>(&h0);
                pk.y = *reinterpret_cast<int*>(&h1);
                pk.z = *reinterpret_cast<int*>(&h2);
                pk.w = *reinterpret_cast<int*>(&h3);
                *reinterpret_cast<int4*>(&C[(size_t)grow * N + cg * 8]) = pk;
            } else {
#pragma unroll
                for (int j = 0; j < 8; ++j) {
                    int c = cg * 8 + j;
                    if (c < N) C[(size_t)grow * N + c] = __float2half(acc[r][j] * sc);
                }
            }
        }
    }
}

// --------------------------- Aggregation --------------------------------
// One wave per node, m pre-scaled by dinv[src] and fp16.
// agg[i] = dinv[i] * (sum_j m'[col] + m'[i]); bias + ReLU fused.
// 8-deep unroll -> 8 outstanding 256B gathers per wave.
__global__ __launch_bounds__(256) void agg_h_kernel(
        const __half* __restrict__ m, const int* __restrict__ col,
        const int* __restrict__ start, const int* __restrict__ cnt,
        const float* __restrict__ dinv, const float* __restrict__ bias,
        float* __restrict__ out, int N) {
    int w = (int)((blockIdx.x * 256 + threadIdx.x) >> 6);
    int lane = threadIdx.x & 63;
    if (w >= N) return;
    const __half2* mp = reinterpret_cast<const __half2*>(m);
    int s = start[w];
    int e = s + cnt[w];
    float ax = 0.f, ay = 0.f, bx = 0.f, by = 0.f;
    int p = s;
    for (; p + 8 <= e; p += 8) {
        int j[8];
#pragma unroll
        for (int u = 0; u < 8; ++u) j[u] = col[p + u];
        __half2 v[8];
#pragma unroll
        for (int u = 0; u < 8; ++u) v[u] = mp[j[u] * 64 + lane];
#pragma unroll
        for (int u = 0; u < 8; ++u) {
            float2 f = __half22float2(v[u]);
            if (u & 1) { bx += f.x; by += f.y; }
            else       { ax += f.x; ay += f.y; }
        }
    }
    for (; p < e; ++p) {
        float2 f = __half22float2(mp[col[p] * 64 + lane]);
        ax += f.x; ay += f.y;
    }
    float2 fi = __half22float2(mp[w * 64 + lane]);
    ax += fi.x; ay += fi.y;
    float di = dinv[w];
    float2 o;
    o.x = fmaxf(fmaf(di, ax + bx, bias[lane * 2]), 0.f);
    o.y = fmaxf(fmaf(di, ay + by, bias[lane * 2 + 1]), 0.f);
    *reinterpret_cast<float2*>(&out[(size_t)w * NHID + lane * 2]) = o;
}

// Final layer: F=40 fp16 m + bias + ReLU + log_softmax (wave shuffle reduce).
__global__ __launch_bounds__(256) void agg_out_kernel(
        const __half* __restrict__ m, const int* __restrict__ col,
        const int* __restrict__ start, const int* __restrict__ cnt,
        const float* __restrict__ dinv, const float* __restrict__ bias,
        float* __restrict__ out, int N) {
    int w = (int)((blockIdx.x * 256 + threadIdx.x) >> 6);
    int lane = threadIdx.x & 63;
    if (w >= N) return;
    bool act = lane < NCLASS;
    int cl = act ? lane : 0;
    int s = start[w];
    int e = s + cnt[w];
    float a0 = 0.f, a1 = 0.f;
    int p = s;
    for (; p + 8 <= e; p += 8) {
        int j[8];
#pragma unroll
        for (int u = 0; u < 8; ++u) j[u] = col[p + u];
        __half v[8];
#pragma unroll
        for (int u = 0; u < 8; ++u) v[u] = m[j[u] * NCLASS + cl];
#pragma unroll
        for (int u = 0; u < 8; ++u) {
            if (u & 1) a1 += __half2float(v[u]);
            else       a0 += __half2float(v[u]);
        }
    }
    for (; p < e; ++p) a0 += __half2float(m[col[p] * NCLASS + cl]);
    a0 += __half2float(m[w * NCLASS + cl]);
    float di = dinv[w];
    float h = fmaxf(fmaf(di, a0 + a1, bias[cl]), 0.f);
    float hm = act ? h : -INFINITY;
#pragma unroll
    for (int off = 32; off; off >>= 1) hm = fmaxf(hm, __shfl_xor(hm, off, 64));
    float ex = act ? expf(h - hm) : 0.f;
    float se = ex;
#pragma unroll
    for (int off = 32; off; off >>= 1) se += __shfl_xor(se, off, 64);
    if (act) out[(size_t)w * NCLASS + lane] = h - hm - logf(se);
}

// ------------------------------ launch -----------------------------------

extern "C" void kernel_launch(void* const* d_in, const int* in_sizes, int n_in,
                              void* d_out, int out_size, void* d_ws, size_t ws_size,
                              hipStream_t stream) {
    const float* x  = (const float*)d_in[0];
    const int*   ei = (const int*)d_in[1];
    const float* W0 = (const float*)d_in[2];
    const float* b0 = (const float*)d_in[3];
    const float* W1 = (const float*)d_in[4];
    const float* b1 = (const float*)d_in[5];
    const float* W2 = (const float*)d_in[6];
    const float* b2 = (const float*)d_in[7];
    float* out = (float*)d_out;

    const int NFEATr = 256;
    const int N = in_sizes[0] / NFEATr;  // 100000
    const int E = in_sizes[1] / 2;       // 1600000
    const int* src = ei;
    const int* dst = ei + E;

    char* p = (char*)d_ws;
    auto alloc = [&](size_t bytes) -> void* {
        void* r = (void*)p;
        p += (bytes + 255) & ~(size_t)255;
        return r;
    };
    int*    cnt    = (int*)alloc((size_t)N * 4);
    int*    start  = (int*)alloc((size_t)N * 4);
    int*    cursor = (int*)alloc((size_t)N * 4);
    float*  dinv   = (float*)alloc((size_t)N * 4);
    int*    total  = (int*)alloc(256);
    int*    col    = (int*)alloc((size_t)E * 4);
    __half* mbuf   = (__half*)alloc((size_t)N * NHID * 2);   // fp16 pre-scaled messages
    float*  hbuf   = (float*)alloc((size_t)N * NHID * 4);

    hipMemsetAsync(cnt, 0, (size_t)N * 4, stream);
    hipMemsetAsync(total, 0, 4, stream);

    int ebl = (E + 255) / 256;
    int nbl = (N + 255) / 256;
    hist_kernel<<<ebl, 256, 0, stream>>>(dst, cnt, E);
    build_nodes_kernel<<<nbl, 256, 0, stream>>>(cnt, start, cursor, dinv, total, N);
    fill_kernel<<<ebl, 256, 0, stream>>>(src, dst, cursor, col, E);

    int gbl64 = (N + 63) / 64;
    int gbl128 = (N + 127) / 128;
    int abl = (N + 3) / 4;  // 4 waves/block, 1 node/wave

    // layer 0
    gemm_kernel<256, 128, 16, 16, false><<<gbl64, 256, 0, stream>>>(x, W0, dinv, mbuf, N, NHID);
    agg_h_kernel<<<abl, 256, 0, stream>>>(mbuf, col, start, cnt, dinv, b0, hbuf, N);

    // layer 1
    gemm_kernel<128, 128, 16, 16, false><<<gbl64, 256, 0, stream>>>(hbuf, W1, dinv, mbuf, N, NHID);
    agg_h_kernel<<<abl, 256, 0, stream>>>(mbuf, col, start, cnt, dinv, b1, hbuf, N);

    // layer 2 (40-wide messages)
    gemm_kernel<128, 64, 8, 32, true><<<gbl128, 256, 0, stream>>>(hbuf, W2, dinv, mbuf, N, NCLASS);
    agg_out_kernel<<<abl, 256, 0, stream>>>(mbuf, col, start, cnt, dinv, b2, out, N);
}

// Round 3
// 480.714 us; speedup vs baseline: 1.8747x; 1.2777x over previous
//
#include <hip/hip_runtime.h>
#include <hip/hip_bf16.h>
#include <hip/hip_fp16.h>
#include <math.h>

#define NHID 128
#define NCLASS 40
#define NWIN 8   // dst-windows for CSR build locality

typedef _Float16 f16;
typedef f16 f16x8 __attribute__((ext_vector_type(8)));
typedef float f32x4 __attribute__((ext_vector_type(4)));

// ----------------------------- CSR build --------------------------------
// Windowed: process dst-ranges so cnt/cursor (50KB) and col window (800KB)
// stay L2-resident per XCD -> scattered writes merge before writeback.

__global__ __launch_bounds__(256) void hist_kernel(const int* __restrict__ dst,
                                                   int* __restrict__ cnt, int E, int win) {
    int stride = gridDim.x * 256;
    for (int w = 0; w < NWIN; ++w) {
        int lo = w * win, hi = lo + win;
        for (int e = blockIdx.x * 256 + threadIdx.x; e < E; e += stride) {
            int d = dst[e];
            if (d >= lo && d < hi) atomicAdd(&cnt[d], 1);
        }
    }
}

__global__ __launch_bounds__(256) void build_nodes_kernel(
        const int* __restrict__ cnt, int* __restrict__ start,
        int* __restrict__ cursor, float* __restrict__ dinv,
        int* __restrict__ total, int N) {
    int i = blockIdx.x * 256 + threadIdx.x;
    int v = (i < N) ? cnt[i] : 0;
    __shared__ int sc[256];
    sc[threadIdx.x] = v;
    __syncthreads();
    for (int off = 1; off < 256; off <<= 1) {
        int t = (threadIdx.x >= off) ? sc[threadIdx.x - off] : 0;
        __syncthreads();
        sc[threadIdx.x] += t;
        __syncthreads();
    }
    int incl = sc[threadIdx.x];
    __shared__ int base;
    if (threadIdx.x == 255) base = atomicAdd(total, incl);
    __syncthreads();
    if (i < N) {
        int s = base + incl - v;
        start[i] = s;
        cursor[i] = s;
        dinv[i] = rsqrtf((float)(cnt[i] + 1));  // +1 self-loop
    }
}

__global__ __launch_bounds__(256) void fill_kernel(const int* __restrict__ src,
                                                   const int* __restrict__ dst,
                                                   int* __restrict__ cursor,
                                                   int* __restrict__ col, int E, int win) {
    int stride = gridDim.x * 256;
    for (int w = 0; w < NWIN; ++w) {
        int lo = w * win, hi = lo + win;
        for (int e = blockIdx.x * 256 + threadIdx.x; e < E; e += stride) {
            int d = dst[e];
            if (d >= lo && d < hi) {
                int p = atomicAdd(&cursor[d], 1);
                col[p] = src[e];
            }
        }
    }
}

// --------------------------- MFMA GEMM ----------------------------------
// C[M x N] = dinv[row] * (A[M x K] @ W[K x N]) stored fp16.
// fp16 MFMA 16x16x32, fp32 accum. Block: BM x BN, 4 waves (WM x WN), each
// wave a 64x64 (or 64-row x 64-col) quadrant of 16x16 frags. KC=64 LDS
// tiles, XOR chunk-swizzle (8 x 16B chunks/row) -> ~2-way conflicts.
template <int K, int BM, int BN, int WM, int WN, bool GUARDN, bool AHALF>
__global__ __launch_bounds__(256) void gemm_mfma(const void* __restrict__ Ap,
                                                 const float* __restrict__ W,
                                                 const float* __restrict__ dinv,
                                                 f16* __restrict__ C, int M, int N) {
    constexpr int KC = 64;
    __shared__ f16 As[BM * KC];
    __shared__ f16 Bs[BN * KC];
    __shared__ float sdinv[BM];
    const int t = threadIdx.x;
    const int wid = t >> 6, lane = t & 63;
    const int wm = wid % WM, wn = wid / WM;
    const int row0 = blockIdx.x * BM;

    for (int i = t; i < BM; i += 256) {
        int r = row0 + i;
        sdinv[i] = dinv[r < M ? r : M - 1];
    }

    f32x4 acc[4][4] = {};

    for (int k0 = 0; k0 < K; k0 += KC) {
        // ---- stage A (BM x 64 halfs), swizzled chunks
        if (AHALF) {
            const f16* A = (const f16*)Ap;
#pragma unroll
            for (int i = 0; i < BM / 32; ++i) {
                int g = t + i * 256;
                int r = g >> 3, c = g & 7;
                int grow = row0 + r; if (grow >= M) grow = M - 1;
                f16x8 v = *reinterpret_cast<const f16x8*>(&A[(size_t)grow * K + k0 + c * 8]);
                *reinterpret_cast<f16x8*>(&As[r * 64 + ((c ^ (r & 7)) << 3)]) = v;
            }
        } else {
            const float* A = (const float*)Ap;
#pragma unroll
            for (int i = 0; i < BM / 32; ++i) {
                int g = t + i * 256;
                int r = g >> 3, c = g & 7;
                int grow = row0 + r; if (grow >= M) grow = M - 1;
                const float* s = &A[(size_t)grow * K + k0 + c * 8];
                float4 a = *reinterpret_cast<const float4*>(s);
                float4 b = *reinterpret_cast<const float4*>(s + 4);
                f16x8 v = {(f16)a.x, (f16)a.y, (f16)a.z, (f16)a.w,
                           (f16)b.x, (f16)b.y, (f16)b.z, (f16)b.w};
                *reinterpret_cast<f16x8*>(&As[r * 64 + ((c ^ (r & 7)) << 3)]) = v;
            }
        }
        // ---- stage W transposed: Bs[n][k], swizzled
        if (!GUARDN) {
#pragma unroll
            for (int i = 0; i < BN / 16; ++i) {
                int v = t + i * 256;
                int kk = v / (BN / 4), nq = v % (BN / 4);
                float4 w = *reinterpret_cast<const float4*>(&W[(size_t)(k0 + kk) * N + nq * 4]);
                float ws[4] = {w.x, w.y, w.z, w.w};
#pragma unroll
                for (int j = 0; j < 4; ++j) {
                    int n = nq * 4 + j;
                    Bs[n * 64 + (((kk >> 3) ^ (n & 7)) << 3) + (kk & 7)] = (f16)ws[j];
                }
            }
        } else {
#pragma unroll
            for (int i = 0; i < BN / 16; ++i) {
                int v = t + i * 256;
                int kk = v / (BN / 4), nq = v % (BN / 4);
#pragma unroll
                for (int j = 0; j < 4; ++j) {
                    int n = nq * 4 + j;
                    float wv = (n < N) ? W[(size_t)(k0 + kk) * N + n] : 0.f;
                    Bs[n * 64 + (((kk >> 3) ^ (n & 7)) << 3) + (kk & 7)] = (f16)wv;
                }
            }
        }
        __syncthreads();

#pragma unroll
        for (int s = 0; s < 2; ++s) {  // two K=32 steps per tile
            f16x8 af[4], bf[4];
            int c = s * 4 + (lane >> 4);
#pragma unroll
            for (int mf = 0; mf < 4; ++mf) {
                int r = wm * 64 + mf * 16 + (lane & 15);
                af[mf] = *reinterpret_cast<const f16x8*>(&As[r * 64 + ((c ^ (r & 7)) << 3)]);
            }
#pragma unroll
            for (int nf = 0; nf < 4; ++nf) {
                int n = wn * 64 + nf * 16 + (lane & 15);
                bf[nf] = *reinterpret_cast<const f16x8*>(&Bs[n * 64 + ((c ^ (n & 7)) << 3)]);
            }
#pragma unroll
            for (int mf = 0; mf < 4; ++mf)
#pragma unroll
                for (int nf = 0; nf < 4; ++nf)
                    acc[mf][nf] = __builtin_amdgcn_mfma_f32_16x16x32_f16(af[mf], bf[nf],
                                                                         acc[mf][nf], 0, 0, 0);
        }
        __syncthreads();
    }

    // epilogue: scale by dinv[row], store fp16
#pragma unroll
    for (int mf = 0; mf < 4; ++mf) {
#pragma unroll
        for (int q = 0; q < 4; ++q) {
            int lr = wm * 64 + mf * 16 + (lane >> 4) * 4 + q;
            int grow = row0 + lr;
            if (grow < M) {
                float scl = sdinv[lr];
#pragma unroll
                for (int nf = 0; nf < 4; ++nf) {
                    int gcol = wn * 64 + nf * 16 + (lane & 15);
                    if (!GUARDN || gcol < N)
                        C[(size_t)grow * N + gcol] = (f16)(acc[mf][nf][q] * scl);
                }
            }
        }
    }
}

// --------------------------- Aggregation --------------------------------
__global__ __launch_bounds__(256) void agg_h_kernel(
        const __half* __restrict__ m, const int* __restrict__ col,
        const int* __restrict__ start, const int* __restrict__ cnt,
        const float* __restrict__ dinv, const float* __restrict__ bias,
        __half* __restrict__ out, int N) {
    int w = (int)((blockIdx.x * 256 + threadIdx.x) >> 6);
    int lane = threadIdx.x & 63;
    if (w >= N) return;
    const __half2* mp = reinterpret_cast<const __half2*>(m);
    int s = start[w];
    int e = s + cnt[w];
    float ax = 0.f, ay = 0.f, bx = 0.f, by = 0.f;
    int p = s;
    for (; p + 8 <= e; p += 8) {
        int j[8];
#pragma unroll
        for (int u = 0; u < 8; ++u) j[u] = col[p + u];
        __half2 v[8];
#pragma unroll
        for (int u = 0; u < 8; ++u) v[u] = mp[j[u] * 64 + lane];
#pragma unroll
        for (int u = 0; u < 8; ++u) {
            float2 f = __half22float2(v[u]);
            if (u & 1) { bx += f.x; by += f.y; }
            else       { ax += f.x; ay += f.y; }
        }
    }
    for (; p < e; ++p) {
        float2 f = __half22float2(mp[col[p] * 64 + lane]);
        ax += f.x; ay += f.y;
    }
    float2 fi = __half22float2(mp[w * 64 + lane]);
    ax += fi.x; ay += fi.y;
    float di = dinv[w];
    float ox = fmaxf(fmaf(di, ax + bx, bias[lane * 2]), 0.f);
    float oy = fmaxf(fmaf(di, ay + by, bias[lane * 2 + 1]), 0.f);
    reinterpret_cast<__half2*>(out)[w * 64 + lane] = __floats2half2_rn(ox, oy);
}

__global__ __launch_bounds__(256) void agg_out_kernel(
        const __half* __restrict__ m, const int* __restrict__ col,
        const int* __restrict__ start, const int* __restrict__ cnt,
        const float* __restrict__ dinv, const float* __restrict__ bias,
        float* __restrict__ out, int N) {
    int w = (int)((blockIdx.x * 256 + threadIdx.x) >> 6);
    int lane = threadIdx.x & 63;
    if (w >= N) return;
    bool act = lane < NCLASS;
    int cl = act ? lane : 0;
    int s = start[w];
    int e = s + cnt[w];
    float a0 = 0.f, a1 = 0.f;
    int p = s;
    for (; p + 8 <= e; p += 8) {
        int j[8];
#pragma unroll
        for (int u = 0; u < 8; ++u) j[u] = col[p + u];
        __half v[8];
#pragma unroll
        for (int u = 0; u < 8; ++u) v[u] = m[j[u] * NCLASS + cl];
#pragma unroll
        for (int u = 0; u < 8; ++u) {
            if (u & 1) a1 += __half2float(v[u]);
            else       a0 += __half2float(v[u]);
        }
    }
    for (; p < e; ++p) a0 += __half2float(m[col[p] * NCLASS + cl]);
    a0 += __half2float(m[w * NCLASS + cl]);
    float di = dinv[w];
    float h = fmaxf(fmaf(di, a0 + a1, bias[cl]), 0.f);
    float hm = act ? h : -INFINITY;
#pragma unroll
    for (int off = 32; off; off >>= 1) hm = fmaxf(hm, __shfl_xor(hm, off, 64));
    float ex = act ? expf(h - hm) : 0.f;
    float se = ex;
#pragma unroll
    for (int off = 32; off; off >>= 1) se += __shfl_xor(se, off, 64);
    if (act) out[(size_t)w * NCLASS + lane] = h - hm - logf(se);
}

// ------------------------------ launch -----------------------------------

extern "C" void kernel_launch(void* const* d_in, const int* in_sizes, int n_in,
                              void* d_out, int out_size, void* d_ws, size_t ws_size,
                              hipStream_t stream) {
    const float* x  = (const float*)d_in[0];
    const int*   ei = (const int*)d_in[1];
    const float* W0 = (const float*)d_in[2];
    const float* b0 = (const float*)d_in[3];
    const float* W1 = (const float*)d_in[4];
    const float* b1 = (const float*)d_in[5];
    const float* W2 = (const float*)d_in[6];
    const float* b2 = (const float*)d_in[7];
    float* out = (float*)d_out;

    const int NFEATr = 256;
    const int N = in_sizes[0] / NFEATr;  // 100000
    const int E = in_sizes[1] / 2;       // 1600000
    const int* src = ei;
    const int* dst = ei + E;

    char* p = (char*)d_ws;
    auto alloc = [&](size_t bytes) -> void* {
        void* r = (void*)p;
        p += (bytes + 255) & ~(size_t)255;
        return r;
    };
    int*    cnt    = (int*)alloc((size_t)N * 4);
    int*    start  = (int*)alloc((size_t)N * 4);
    int*    cursor = (int*)alloc((size_t)N * 4);
    float*  dinv   = (float*)alloc((size_t)N * 4);
    int*    total  = (int*)alloc(256);
    int*    col    = (int*)alloc((size_t)E * 4);
    f16*    mbuf   = (f16*)alloc((size_t)N * NHID * 2);
    f16*    hbuf   = (f16*)alloc((size_t)N * NHID * 2);

    hipMemsetAsync(cnt, 0, (size_t)N * 4, stream);
    hipMemsetAsync(total, 0, 4, stream);

    int win = (N + NWIN - 1) / NWIN;
    int nbl = (N + 255) / 256;
    hist_kernel<<<2048, 256, 0, stream>>>(dst, cnt, E, win);
    build_nodes_kernel<<<nbl, 256, 0, stream>>>(cnt, start, cursor, dinv, total, N);
    fill_kernel<<<2048, 256, 0, stream>>>(src, dst, cursor, col, E, win);

    int abl = (N + 3) / 4;  // 4 waves/block, 1 node/wave
    int g128 = (N + 127) / 128;
    int g256 = (N + 255) / 256;

    // layer 0: x fp32 [N,256] @ W0 -> mbuf f16 (pre-scaled)
    gemm_mfma<256, 128, 128, 2, 2, false, false><<<g128, 256, 0, stream>>>(
        (const void*)x, W0, dinv, mbuf, N, NHID);
    agg_h_kernel<<<abl, 256, 0, stream>>>((const __half*)mbuf, col, start, cnt, dinv, b0,
                                          (__half*)hbuf, N);

    // layer 1: hbuf f16 [N,128] @ W1 -> mbuf
    gemm_mfma<128, 128, 128, 2, 2, false, true><<<g128, 256, 0, stream>>>(
        (const void*)hbuf, W1, dinv, mbuf, N, NHID);
    agg_h_kernel<<<abl, 256, 0, stream>>>((const __half*)mbuf, col, start, cnt, dinv, b1,
                                          (__half*)hbuf, N);

    // layer 2: hbuf f16 [N,128] @ W2[128,40] -> mbuf (40-wide)
    gemm_mfma<128, 256, 64, 4, 1, true, true><<<g256, 256, 0, stream>>>(
        (const void*)hbuf, W2, dinv, mbuf, N, NCLASS);
    agg_out_kernel<<<abl, 256, 0, stream>>>((const __half*)mbuf, col, start, cnt, dinv, b2,
                                            out, N);
}

// Round 4
// 378.258 us; speedup vs baseline: 2.3825x; 1.2709x over previous
//
#include <hip/hip_runtime.h>
#include <hip/hip_bf16.h>
#include <hip/hip_fp16.h>
#include <math.h>

#define NHID 128
#define NCLASS 40
#define NBLK 256          // edge-chunk blocks for bucket passes
#define MAXBUK 1600       // >= ceil(N/64)

typedef _Float16 f16;
typedef f16 f16x8 __attribute__((ext_vector_type(8)));
typedef float f32x4 __attribute__((ext_vector_type(4)));

// ---------------- CSR build: 2-level counting sort (LDS atomics only) ----

// Pass A: per-block coarse histogram (bucket = dst>>6), LDS atomics.
__global__ __launch_bounds__(256) void bucket_hist(const int* __restrict__ dst,
                                                   int* __restrict__ bh,
                                                   int E, int nbuk, int chunk) {
    __shared__ int h[MAXBUK];
    for (int i = threadIdx.x; i < nbuk; i += 256) h[i] = 0;
    __syncthreads();
    int b = blockIdx.x;
    int lo = b * chunk, hi = min(E, lo + chunk);
    for (int e = lo + threadIdx.x; e < hi; e += 256) atomicAdd(&h[dst[e] >> 6], 1);
    __syncthreads();
    for (int i = threadIdx.x; i < nbuk; i += 256) bh[(size_t)b * nbuk + i] = h[i];
}

// K1: per-bucket totals across blocks.
__global__ __launch_bounds__(256) void bucket_total(const int* __restrict__ bh,
                                                    int* __restrict__ T, int nbuk) {
    int buk = blockIdx.x * 256 + threadIdx.x;
    if (buk >= nbuk) return;
    int s = 0;
    for (int b = 0; b < NBLK; ++b) s += bh[(size_t)b * nbuk + buk];
    T[buk] = s;
}

// K2: exclusive scan over buckets (single block).
__global__ __launch_bounds__(256) void bucket_scan(const int* __restrict__ T,
                                                   int* __restrict__ BB, int nbuk, int E) {
    __shared__ int sc[256];
    __shared__ int carry;
    if (threadIdx.x == 0) carry = 0;
    __syncthreads();
    for (int base = 0; base < nbuk; base += 256) {
        int i = base + threadIdx.x;
        int v = (i < nbuk) ? T[i] : 0;
        sc[threadIdx.x] = v;
        __syncthreads();
        for (int off = 1; off < 256; off <<= 1) {
            int t = (threadIdx.x >= off) ? sc[threadIdx.x - off] : 0;
            __syncthreads();
            sc[threadIdx.x] += t;
            __syncthreads();
        }
        if (i < nbuk) BB[i] = carry + sc[threadIdx.x] - v;
        __syncthreads();
        if (threadIdx.x == 255) carry += sc[255];
        __syncthreads();
    }
    if (threadIdx.x == 0) BB[nbuk] = E;
}

// K3: per-(block,bucket) start offsets.
__global__ __launch_bounds__(256) void bucket_expand(const int* __restrict__ bh,
                                                     const int* __restrict__ BB,
                                                     int* __restrict__ off, int nbuk) {
    int buk = blockIdx.x * 256 + threadIdx.x;
    if (buk >= nbuk) return;
    int run = BB[buk];
    for (int b = 0; b < NBLK; ++b) {
        off[(size_t)b * nbuk + buk] = run;
        run += bh[(size_t)b * nbuk + buk];
    }
}

// Pass C: scatter (src,dst) pairs grouped by bucket, LDS cursors.
__global__ __launch_bounds__(256) void bucket_scatter(const int* __restrict__ src,
                                                      const int* __restrict__ dst,
                                                      const int* __restrict__ off,
                                                      int2* __restrict__ eb,
                                                      int E, int nbuk, int chunk) {
    __shared__ int cur[MAXBUK];
    int b = blockIdx.x;
    for (int i = threadIdx.x; i < nbuk; i += 256) cur[i] = off[(size_t)b * nbuk + i];
    __syncthreads();
    int lo = b * chunk, hi = min(E, lo + chunk);
    for (int e = lo + threadIdx.x; e < hi; e += 256) {
        int d = dst[e], s = src[e];
        int pos = atomicAdd(&cur[d >> 6], 1);
        eb[pos] = make_int2(s, d);
    }
}

// Pass D: exact CSR within each 64-node bucket; start/dinv/col. LDS atomics.
__global__ __launch_bounds__(256) void bucket_csr(const int2* __restrict__ eb,
                                                  const int* __restrict__ BB,
                                                  int* __restrict__ startA,
                                                  float* __restrict__ dinv,
                                                  int* __restrict__ col,
                                                  int N, int E) {
    __shared__ int h[64];
    int b = blockIdx.x;
    int bs = BB[b], be = BB[b + 1];
    if (threadIdx.x < 64) h[threadIdx.x] = 0;
    __syncthreads();
    for (int i = bs + threadIdx.x; i < be; i += 256) atomicAdd(&h[eb[i].y & 63], 1);
    __syncthreads();
    if (threadIdx.x < 64) {  // threads 0..63 = wave 0
        int v = h[threadIdx.x];
        int incl = v;
#pragma unroll
        for (int o = 1; o < 64; o <<= 1) {
            int t = __shfl_up(incl, o, 64);
            if ((int)threadIdx.x >= o) incl += t;
        }
        int n = (b << 6) + threadIdx.x;
        if (n < N) {
            startA[n] = bs + incl - v;
            dinv[n] = rsqrtf((float)(v + 1));  // +1 self-loop
        }
        h[threadIdx.x] = incl - v;  // reuse as cursor
    }
    __syncthreads();
    for (int i = bs + threadIdx.x; i < be; i += 256) {
        int2 p = eb[i];
        int pos = bs + atomicAdd(&h[p.y & 63], 1);
        col[pos] = p.x;
    }
    if (b == 0 && threadIdx.x == 0) startA[N] = E;
}

// --------------------------- MFMA GEMM ----------------------------------
template <int K, int BM, int BN, int WM, int WN, bool GUARDN, bool AHALF>
__global__ __launch_bounds__(256) void gemm_mfma(const void* __restrict__ Ap,
                                                 const float* __restrict__ W,
                                                 const float* __restrict__ dinv,
                                                 f16* __restrict__ C, int M, int N) {
    constexpr int KC = 64;
    __shared__ f16 As[BM * KC];
    __shared__ f16 Bs[BN * KC];
    __shared__ float sdinv[BM];
    const int t = threadIdx.x;
    const int wid = t >> 6, lane = t & 63;
    const int wm = wid % WM, wn = wid / WM;
    const int row0 = blockIdx.x * BM;

    for (int i = t; i < BM; i += 256) {
        int r = row0 + i;
        sdinv[i] = dinv[r < M ? r : M - 1];
    }

    f32x4 acc[4][4] = {};

    for (int k0 = 0; k0 < K; k0 += KC) {
        if (AHALF) {
            const f16* A = (const f16*)Ap;
#pragma unroll
            for (int i = 0; i < BM / 32; ++i) {
                int g = t + i * 256;
                int r = g >> 3, c = g & 7;
                int grow = row0 + r; if (grow >= M) grow = M - 1;
                f16x8 v = *reinterpret_cast<const f16x8*>(&A[(size_t)grow * K + k0 + c * 8]);
                *reinterpret_cast<f16x8*>(&As[r * 64 + ((c ^ (r & 7)) << 3)]) = v;
            }
        } else {
            const float* A = (const float*)Ap;
#pragma unroll
            for (int i = 0; i < BM / 32; ++i) {
                int g = t + i * 256;
                int r = g >> 3, c = g & 7;
                int grow = row0 + r; if (grow >= M) grow = M - 1;
                const float* s = &A[(size_t)grow * K + k0 + c * 8];
                float4 a = *reinterpret_cast<const float4*>(s);
                float4 b = *reinterpret_cast<const float4*>(s + 4);
                f16x8 v = {(f16)a.x, (f16)a.y, (f16)a.z, (f16)a.w,
                           (f16)b.x, (f16)b.y, (f16)b.z, (f16)b.w};
                *reinterpret_cast<f16x8*>(&As[r * 64 + ((c ^ (r & 7)) << 3)]) = v;
            }
        }
        if (!GUARDN) {
#pragma unroll
            for (int i = 0; i < BN / 16; ++i) {
                int v = t + i * 256;
                int kk = v / (BN / 4), nq = v % (BN / 4);
                float4 w = *reinterpret_cast<const float4*>(&W[(size_t)(k0 + kk) * N + nq * 4]);
                float ws[4] = {w.x, w.y, w.z, w.w};
#pragma unroll
                for (int j = 0; j < 4; ++j) {
                    int n = nq * 4 + j;
                    Bs[n * 64 + (((kk >> 3) ^ (n & 7)) << 3) + (kk & 7)] = (f16)ws[j];
                }
            }
        } else {
#pragma unroll
            for (int i = 0; i < BN / 16; ++i) {
                int v = t + i * 256;
                int kk = v / (BN / 4), nq = v % (BN / 4);
#pragma unroll
                for (int j = 0; j < 4; ++j) {
                    int n = nq * 4 + j;
                    float wv = (n < N) ? W[(size_t)(k0 + kk) * N + n] : 0.f;
                    Bs[n * 64 + (((kk >> 3) ^ (n & 7)) << 3) + (kk & 7)] = (f16)wv;
                }
            }
        }
        __syncthreads();

#pragma unroll
        for (int s = 0; s < 2; ++s) {
            f16x8 af[4], bf[4];
            int c = s * 4 + (lane >> 4);
#pragma unroll
            for (int mf = 0; mf < 4; ++mf) {
                int r = wm * 64 + mf * 16 + (lane & 15);
                af[mf] = *reinterpret_cast<const f16x8*>(&As[r * 64 + ((c ^ (r & 7)) << 3)]);
            }
#pragma unroll
            for (int nf = 0; nf < 4; ++nf) {
                int n = wn * 64 + nf * 16 + (lane & 15);
                bf[nf] = *reinterpret_cast<const f16x8*>(&Bs[n * 64 + ((c ^ (n & 7)) << 3)]);
            }
#pragma unroll
            for (int mf = 0; mf < 4; ++mf)
#pragma unroll
                for (int nf = 0; nf < 4; ++nf)
                    acc[mf][nf] = __builtin_amdgcn_mfma_f32_16x16x32_f16(af[mf], bf[nf],
                                                                         acc[mf][nf], 0, 0, 0);
        }
        __syncthreads();
    }

#pragma unroll
    for (int mf = 0; mf < 4; ++mf) {
#pragma unroll
        for (int q = 0; q < 4; ++q) {
            int lr = wm * 64 + mf * 16 + (lane >> 4) * 4 + q;
            int grow = row0 + lr;
            if (grow < M) {
                float scl = sdinv[lr];
#pragma unroll
                for (int nf = 0; nf < 4; ++nf) {
                    int gcol = wn * 64 + nf * 16 + (lane & 15);
                    if (!GUARDN || gcol < N)
                        C[(size_t)grow * N + gcol] = (f16)(acc[mf][nf][q] * scl);
                }
            }
        }
    }
}

// --------------------------- Aggregation --------------------------------
__global__ __launch_bounds__(256) void agg_h_kernel(
        const __half* __restrict__ m, const int* __restrict__ col,
        const int* __restrict__ start,
        const float* __restrict__ dinv, const float* __restrict__ bias,
        __half* __restrict__ out, int N) {
    int w = (int)((blockIdx.x * 256 + threadIdx.x) >> 6);
    int lane = threadIdx.x & 63;
    if (w >= N) return;
    const __half2* mp = reinterpret_cast<const __half2*>(m);
    int s = start[w];
    int e = start[w + 1];
    float ax = 0.f, ay = 0.f, bx = 0.f, by = 0.f;
    int p = s;
    for (; p + 8 <= e; p += 8) {
        int j[8];
#pragma unroll
        for (int u = 0; u < 8; ++u) j[u] = col[p + u];
        __half2 v[8];
#pragma unroll
        for (int u = 0; u < 8; ++u) v[u] = mp[j[u] * 64 + lane];
#pragma unroll
        for (int u = 0; u < 8; ++u) {
            float2 f = __half22float2(v[u]);
            if (u & 1) { bx += f.x; by += f.y; }
            else       { ax += f.x; ay += f.y; }
        }
    }
    for (; p < e; ++p) {
        float2 f = __half22float2(mp[col[p] * 64 + lane]);
        ax += f.x; ay += f.y;
    }
    float2 fi = __half22float2(mp[w * 64 + lane]);
    ax += fi.x; ay += fi.y;
    float di = dinv[w];
    float ox = fmaxf(fmaf(di, ax + bx, bias[lane * 2]), 0.f);
    float oy = fmaxf(fmaf(di, ay + by, bias[lane * 2 + 1]), 0.f);
    reinterpret_cast<__half2*>(out)[w * 64 + lane] = __floats2half2_rn(ox, oy);
}

__global__ __launch_bounds__(256) void agg_out_kernel(
        const __half* __restrict__ m, const int* __restrict__ col,
        const int* __restrict__ start,
        const float* __restrict__ dinv, const float* __restrict__ bias,
        float* __restrict__ out, int N) {
    int w = (int)((blockIdx.x * 256 + threadIdx.x) >> 6);
    int lane = threadIdx.x & 63;
    if (w >= N) return;
    bool act = lane < NCLASS;
    int cl = act ? lane : 0;
    int s = start[w];
    int e = start[w + 1];
    float a0 = 0.f, a1 = 0.f;
    int p = s;
    for (; p + 8 <= e; p += 8) {
        int j[8];
#pragma unroll
        for (int u = 0; u < 8; ++u) j[u] = col[p + u];
        __half v[8];
#pragma unroll
        for (int u = 0; u < 8; ++u) v[u] = m[j[u] * NCLASS + cl];
#pragma unroll
        for (int u = 0; u < 8; ++u) {
            if (u & 1) a1 += __half2float(v[u]);
            else       a0 += __half2float(v[u]);
        }
    }
    for (; p < e; ++p) a0 += __half2float(m[col[p] * NCLASS + cl]);
    a0 += __half2float(m[w * NCLASS + cl]);
    float di = dinv[w];
    float h = fmaxf(fmaf(di, a0 + a1, bias[cl]), 0.f);
    float hm = act ? h : -INFINITY;
#pragma unroll
    for (int off = 32; off; off >>= 1) hm = fmaxf(hm, __shfl_xor(hm, off, 64));
    float ex = act ? expf(h - hm) : 0.f;
    float se = ex;
#pragma unroll
    for (int off = 32; off; off >>= 1) se += __shfl_xor(se, off, 64);
    if (act) out[(size_t)w * NCLASS + lane] = h - hm - logf(se);
}

// ------------------------------ launch -----------------------------------

extern "C" void kernel_launch(void* const* d_in, const int* in_sizes, int n_in,
                              void* d_out, int out_size, void* d_ws, size_t ws_size,
                              hipStream_t stream) {
    const float* x  = (const float*)d_in[0];
    const int*   ei = (const int*)d_in[1];
    const float* W0 = (const float*)d_in[2];
    const float* b0 = (const float*)d_in[3];
    const float* W1 = (const float*)d_in[4];
    const float* b1 = (const float*)d_in[5];
    const float* W2 = (const float*)d_in[6];
    const float* b2 = (const float*)d_in[7];
    float* out = (float*)d_out;

    const int NFEATr = 256;
    const int N = in_sizes[0] / NFEATr;  // 100000
    const int E = in_sizes[1] / 2;       // 1600000
    const int* src = ei;
    const int* dst = ei + E;

    const int nbuk = (N + 63) >> 6;      // 1563
    const int chunk = (E + NBLK - 1) / NBLK;

    char* p = (char*)d_ws;
    auto alloc = [&](size_t bytes) -> void* {
        void* r = (void*)p;
        p += (bytes + 255) & ~(size_t)255;
        return r;
    };
    int*    bh     = (int*)alloc((size_t)NBLK * nbuk * 4);
    int*    T      = (int*)alloc((size_t)nbuk * 4);
    int*    BB     = (int*)alloc((size_t)(nbuk + 1) * 4);
    int*    offb   = (int*)alloc((size_t)NBLK * nbuk * 4);
    int2*   eb     = (int2*)alloc((size_t)E * 8);
    int*    col    = (int*)alloc((size_t)E * 4);
    int*    startA = (int*)alloc((size_t)(N + 1) * 4);
    float*  dinv   = (float*)alloc((size_t)N * 4);
    f16*    mbuf   = (f16*)alloc((size_t)N * NHID * 2);
    f16*    hbuf   = (f16*)alloc((size_t)N * NHID * 2);

    int nbl7 = (nbuk + 255) / 256;

    bucket_hist<<<NBLK, 256, 0, stream>>>(dst, bh, E, nbuk, chunk);
    bucket_total<<<nbl7, 256, 0, stream>>>(bh, T, nbuk);
    bucket_scan<<<1, 256, 0, stream>>>(T, BB, nbuk, E);
    bucket_expand<<<nbl7, 256, 0, stream>>>(bh, BB, offb, nbuk);
    bucket_scatter<<<NBLK, 256, 0, stream>>>(src, dst, offb, eb, E, nbuk, chunk);
    bucket_csr<<<nbuk, 256, 0, stream>>>(eb, BB, startA, dinv, col, N, E);

    int abl = (N + 3) / 4;
    int g128 = (N + 127) / 128;
    int g256 = (N + 255) / 256;

    // layer 0: x fp32 [N,256] @ W0 -> mbuf f16 (pre-scaled by dinv[row])
    gemm_mfma<256, 128, 128, 2, 2, false, false><<<g128, 256, 0, stream>>>(
        (const void*)x, W0, dinv, mbuf, N, NHID);
    agg_h_kernel<<<abl, 256, 0, stream>>>((const __half*)mbuf, col, startA, dinv, b0,
                                          (__half*)hbuf, N);

    // layer 1
    gemm_mfma<128, 128, 128, 2, 2, false, true><<<g128, 256, 0, stream>>>(
        (const void*)hbuf, W1, dinv, mbuf, N, NHID);
    agg_h_kernel<<<abl, 256, 0, stream>>>((const __half*)mbuf, col, startA, dinv, b1,
                                          (__half*)hbuf, N);

    // layer 2 (40-wide messages)
    gemm_mfma<128, 256, 64, 4, 1, true, true><<<g256, 256, 0, stream>>>(
        (const void*)hbuf, W2, dinv, mbuf, N, NCLASS);
    agg_out_kernel<<<abl, 256, 0, stream>>>((const __half*)mbuf, col, startA, dinv, b2,
                                            out, N);
}